// Round 2
// baseline (571.658 us; speedup 1.0000x reference)
//
#include <hip/hip_runtime.h>
#include <stdint.h>

#define NB 8192
#define ND 2048
#define NE 8
#define NG 4
#define NP 512
#define NH 192

typedef unsigned short u16;
typedef _Float16 half_t;
typedef half_t f16x8 __attribute__((ext_vector_type(8)));
typedef float f32x4 __attribute__((ext_vector_type(4)));

__device__ __forceinline__ void gload16(const void* g, void* l) {
  __builtin_amdgcn_global_load_lds(
      (const __attribute__((address_space(1))) void*)g,
      (__attribute__((address_space(3))) void*)l, 16, 0, 0);
}

// ---------------- x -> fp16 conversion + fp64 row mean ----------------
__global__ __launch_bounds__(256) void k_convert(
    const float* __restrict__ x, half_t* __restrict__ xh, double* __restrict__ qm)
{
  const int b = blockIdx.x;
  const int t = threadIdx.x;
  const float* xr = x + (size_t)b * ND;
  const float4 v0 = ((const float4*)xr)[t * 2];
  const float4 v1 = ((const float4*)xr)[t * 2 + 1];
  float f[8] = {v0.x, v0.y, v0.z, v0.w, v1.x, v1.y, v1.z, v1.w};
  double s = 0.0;
  __align__(16) half_t hb[8];
#pragma unroll
  for (int i = 0; i < 8; i++) { s += (double)f[i]; hb[i] = (half_t)f[i]; }
  *reinterpret_cast<int4*>(xh + (size_t)b * ND + t * 8) = *reinterpret_cast<const int4*>(hb);

  // wave shuffle reduction (64 lanes)
#pragma unroll
  for (int m = 32; m >= 1; m >>= 1) s += __shfl_xor(s, m);
  __shared__ double part[4];
  if ((t & 63) == 0) part[t >> 6] = s;
  __syncthreads();
  if (t == 0) qm[b] = (part[0] + part[1] + part[2] + part[3]) / (double)ND;
}

// ---------------- gating: one wave per row ----------------
__global__ __launch_bounds__(256) void k_gate(
    const double* __restrict__ qm,
    const float* __restrict__ Wg, const float* __restrict__ bg,
    const float* __restrict__ Wp, const float* __restrict__ bp,
    const float* __restrict__ Wgg, const float* __restrict__ bgg,
    int* __restrict__ rowl, float* __restrict__ wl, int* __restrict__ cnt)
{
  const int wave = threadIdx.x >> 6;
  const int lane = threadIdx.x & 63;
  const int b = blockIdx.x * 4 + wave;
  const double q = qm[b];

  double part = 0.0;
#pragma unroll
  for (int i = 0; i < 3; i++) {
    int h = lane + i * 64;  // 0..191
    double ang = q * (7.0 * (double)(h + 1));
    part += cos(ang) + sin(ang);
  }
#pragma unroll
  for (int m = 32; m >= 1; m >>= 1) part += __shfl_xor(part, m);
  const double tm = part / (2.0 * (double)NH);
  const double gi1 = 32.0 / 2048.0;  // mean spike rate is a constant (see R0 analysis)

  // lanes 0..7 each compute one expert logit in fp64
  double lg = -1.0e300;
  if (lane < 8) {
    const int e = lane, g = e & 3;
    lg = tm * (double)Wg[e] + gi1 * (double)Wg[NE + e] + (double)bg[e];
    lg -= 0.1 * (tm * (double)Wp[e] + gi1 * (double)Wp[NE + e] + (double)bp[e]);
    lg += tm * (double)Wgg[g] + gi1 * (double)Wgg[NG + g] + (double)bgg[g];
  }
  double mx = lg;
#pragma unroll
  for (int m = 4; m >= 1; m >>= 1) mx = fmax(mx, __shfl_xor(mx, m));
  double pe = 0.0;
  if (lane < 8) pe = exp(lg - mx);
  double ps = pe;
#pragma unroll
  for (int m = 4; m >= 1; m >>= 1) ps += __shfl_xor(ps, m);

  // gather all 8 logits/probs to every lane (shuffles executed convergently)
  double lgs[8], pes[8];
#pragma unroll
  for (int e = 0; e < 8; e++) { lgs[e] = __shfl(lg, e); pes[e] = __shfl(pe, e); }

  if (lane == 0) {
    int e0 = 0;
    for (int e = 1; e < NE; e++) if (lgs[e] > lgs[e0]) e0 = e;
    int e1 = (e0 == 0) ? 1 : 0;
    for (int e = 0; e < NE; e++) if (e != e0 && lgs[e] > lgs[e1]) e1 = e;
    const double p0 = pes[e0] / ps;
    const double p1 = pes[e1] / ps;
    const double den = p0 + p1 + 1e-9;
    const float w0 = (float)(p0 / den), w1 = (float)(p1 / den);
    int pos0 = atomicAdd(&cnt[e0], 1);
    rowl[e0 * NB + pos0] = b;
    wl[e0 * NB + pos0] = w0;
    int pos1 = atomicAdd(&cnt[8 + e1], 1);
    rowl[(8 + e1) * NB + pos1] = b;
    wl[(8 + e1) * NB + pos1] = w1;
  }
}

// ---------------- weight transpose + fp16 convert ----------------
// which=0: W1 [E][2048][512] -> w1t [E][512][2048]
// which=1: W2 [E][512][2048] -> w2t [E][2048][512]
__global__ __launch_bounds__(256) void k_cvt_w(
    const float* __restrict__ W1, const float* __restrict__ W2,
    half_t* __restrict__ w1t, half_t* __restrict__ w2t)
{
  const int which = blockIdx.y;
  const int R = which ? NP : ND;
  const int C = which ? ND : NP;
  const float* src = which ? W2 : W1;
  half_t* dst = which ? w2t : w1t;
  const int tiles_c = C >> 5;
  const int tiles_per_e = (R >> 5) * tiles_c;
  int id = blockIdx.x;
  int e = id / tiles_per_e;
  int rem = id - e * tiles_per_e;
  int tr = rem / tiles_c, tc = rem - tr * tiles_c;
  __shared__ float tile[32][33];
  const int tx = threadIdx.x & 31, ty = threadIdx.x >> 5;
  const float* s = src + (size_t)e * R * C + (size_t)(tr * 32) * C + tc * 32;
#pragma unroll
  for (int i = 0; i < 4; i++)
    tile[ty + i * 8][tx] = s[(size_t)(ty + i * 8) * C + tx];
  __syncthreads();
  half_t* d = dst + (size_t)e * R * C + (size_t)(tc * 32) * R + tr * 32;
#pragma unroll
  for (int i = 0; i < 4; i++)
    d[(size_t)(ty + i * 8) * R + tx] = (half_t)tile[tx][ty + i * 8];
}

__global__ void k_prefix(const int* __restrict__ cnt, int* __restrict__ pbase) {
  if (threadIdx.x == 0 && blockIdx.x == 0) {
    int s = 0;
    for (int i = 0; i < 16; i++) { pbase[i] = s; s += cnt[i]; }
  }
}

// ---------------- GEMM1: H = relu(gather(x) @ W1[e] + b1[e]) ----------------
__global__ __launch_bounds__(256) void k_gemm1(
    const half_t* __restrict__ xh, const half_t* __restrict__ w1t,
    const float* __restrict__ b1,
    const int* __restrict__ rowl, const int* __restrict__ cnt,
    const int* __restrict__ pbase, half_t* __restrict__ Hbuf)
{
  const int bucket = blockIdx.z;
  const int count = cnt[bucket];
  const int m0 = blockIdx.y * 128;
  if (m0 >= count) return;
  const int e = bucket & 7;
  const int n0 = blockIdx.x * 128;
  const int t = threadIdx.x;

  __shared__ __align__(16) half_t As[128 * 32];
  __shared__ __align__(16) half_t Bs[128 * 32];
  __shared__ int rows_s[128];

  if (t < 128) {
    int mi = m0 + t;
    rows_s[t] = rowl[bucket * NB + (mi < count ? mi : m0)];
  }
  __syncthreads();

  const int w = t >> 6, lane = t & 63;
  const int c0 = w * 128 + lane, c1 = c0 + 64;
  const half_t* gA0 = xh + (size_t)rows_s[c0 >> 2] * ND + (c0 & 3) * 8;
  const half_t* gA1 = xh + (size_t)rows_s[c1 >> 2] * ND + (c1 & 3) * 8;
  const half_t* w1te = w1t + (size_t)e * NP * ND;
  const half_t* gB0 = w1te + (size_t)(n0 + (c0 >> 2)) * ND + (c0 & 3) * 8;
  const half_t* gB1 = w1te + (size_t)(n0 + (c1 >> 2)) * ND + (c1 & 3) * 8;
  half_t* lA0 = As + (w * 128) * 8;
  half_t* lA1 = As + (w * 128 + 64) * 8;
  half_t* lB0 = Bs + (w * 128) * 8;
  half_t* lB1 = Bs + (w * 128 + 64) * 8;

  const int wr = w >> 1, wc = w & 1;
  const int lrow = lane & 15, lk = lane >> 4;

  f32x4 acc[4][4];
#pragma unroll
  for (int i = 0; i < 4; i++)
#pragma unroll
    for (int j = 0; j < 4; j++) {
      acc[i][j][0] = 0.f; acc[i][j][1] = 0.f; acc[i][j][2] = 0.f; acc[i][j][3] = 0.f;
    }

  for (int k0 = 0; k0 < ND; k0 += 32) {
    gload16(gA0 + k0, lA0);
    gload16(gA1 + k0, lA1);
    gload16(gB0 + k0, lB0);
    gload16(gB1 + k0, lB1);
    __syncthreads();
    f16x8 af[4], bf[4];
#pragma unroll
    for (int i = 0; i < 4; i++) {
      af[i] = *reinterpret_cast<const f16x8*>(&As[(wr * 64 + i * 16 + lrow) * 32 + lk * 8]);
      bf[i] = *reinterpret_cast<const f16x8*>(&Bs[(wc * 64 + i * 16 + lrow) * 32 + lk * 8]);
    }
#pragma unroll
    for (int mi = 0; mi < 4; mi++)
#pragma unroll
      for (int ni = 0; ni < 4; ni++)
        acc[mi][ni] = __builtin_amdgcn_mfma_f32_16x16x32_f16(af[mi], bf[ni], acc[mi][ni], 0, 0, 0);
    __syncthreads();
  }

  const int pb = pbase[bucket];
#pragma unroll
  for (int mi = 0; mi < 4; mi++) {
#pragma unroll
    for (int i = 0; i < 4; i++) {
      int lm = wr * 64 + mi * 16 + lk * 4 + i;
      if (m0 + lm < count) {
        size_t prow = (size_t)(pb + m0 + lm) * NP;
#pragma unroll
        for (int ni = 0; ni < 4; ni++) {
          int col = n0 + wc * 64 + ni * 16 + lrow;
          float v = acc[mi][ni][i] + b1[e * NP + col];
          Hbuf[prow + col] = (half_t)(v > 0.f ? v : 0.f);
        }
      }
    }
  }
}

// ---------------- GEMM2: out[r] (=|+=) w * (H @ W2[e] + b2[e]) ----------------
__global__ __launch_bounds__(256) void k_gemm2(
    const half_t* __restrict__ Hbuf, const half_t* __restrict__ w2t,
    const float* __restrict__ b2,
    const int* __restrict__ rowl, const float* __restrict__ wl,
    const int* __restrict__ cnt, const int* __restrict__ pbase,
    float* __restrict__ out, int bucket0, int addmode)
{
  const int bucket = bucket0 + blockIdx.z;
  const int count = cnt[bucket];
  const int m0 = blockIdx.y * 128;
  if (m0 >= count) return;
  const int e = bucket & 7;
  const int n0 = blockIdx.x * 128;
  const int t = threadIdx.x;

  __shared__ __align__(16) half_t As[128 * 32];
  __shared__ __align__(16) half_t Bs[128 * 32];
  __shared__ int rows_s[128];
  __shared__ float ws_s[128];

  if (t < 128) {
    int mi = m0 + t;
    int idx = bucket * NB + (mi < count ? mi : m0);
    rows_s[t] = rowl[idx];
    ws_s[t] = wl[idx];
  }
  __syncthreads();

  const int w = t >> 6, lane = t & 63;
  const int c0 = w * 128 + lane, c1 = c0 + 64;
  const int pb = pbase[bucket];
  const half_t* gA0 = Hbuf + (size_t)(pb + m0 + (c0 >> 2)) * NP + (c0 & 3) * 8;
  const half_t* gA1 = Hbuf + (size_t)(pb + m0 + (c1 >> 2)) * NP + (c1 & 3) * 8;
  const half_t* w2te = w2t + (size_t)e * ND * NP;
  const half_t* gB0 = w2te + (size_t)(n0 + (c0 >> 2)) * NP + (c0 & 3) * 8;
  const half_t* gB1 = w2te + (size_t)(n0 + (c1 >> 2)) * NP + (c1 & 3) * 8;
  half_t* lA0 = As + (w * 128) * 8;
  half_t* lA1 = As + (w * 128 + 64) * 8;
  half_t* lB0 = Bs + (w * 128) * 8;
  half_t* lB1 = Bs + (w * 128 + 64) * 8;

  const int wr = w >> 1, wc = w & 1;
  const int lrow = lane & 15, lk = lane >> 4;

  f32x4 acc[4][4];
#pragma unroll
  for (int i = 0; i < 4; i++)
#pragma unroll
    for (int j = 0; j < 4; j++) {
      acc[i][j][0] = 0.f; acc[i][j][1] = 0.f; acc[i][j][2] = 0.f; acc[i][j][3] = 0.f;
    }

  for (int k0 = 0; k0 < NP; k0 += 32) {
    gload16(gA0 + k0, lA0);
    gload16(gA1 + k0, lA1);
    gload16(gB0 + k0, lB0);
    gload16(gB1 + k0, lB1);
    __syncthreads();
    f16x8 af[4], bf[4];
#pragma unroll
    for (int i = 0; i < 4; i++) {
      af[i] = *reinterpret_cast<const f16x8*>(&As[(wr * 64 + i * 16 + lrow) * 32 + lk * 8]);
      bf[i] = *reinterpret_cast<const f16x8*>(&Bs[(wc * 64 + i * 16 + lrow) * 32 + lk * 8]);
    }
#pragma unroll
    for (int mi = 0; mi < 4; mi++)
#pragma unroll
      for (int ni = 0; ni < 4; ni++)
        acc[mi][ni] = __builtin_amdgcn_mfma_f32_16x16x32_f16(af[mi], bf[ni], acc[mi][ni], 0, 0, 0);
    __syncthreads();
  }

#pragma unroll
  for (int mi = 0; mi < 4; mi++) {
#pragma unroll
    for (int i = 0; i < 4; i++) {
      int lm = wr * 64 + mi * 16 + lk * 4 + i;
      if (m0 + lm < count) {
        int r = rows_s[lm];
        float wgt = ws_s[lm];
        float* orow = out + (size_t)r * ND;
#pragma unroll
        for (int ni = 0; ni < 4; ni++) {
          int col = n0 + wc * 64 + ni * 16 + lrow;
          float v = (acc[mi][ni][i] + b2[e * ND + col]) * wgt;
          if (addmode) orow[col] += v;
          else orow[col] = v;
        }
      }
    }
  }
}

extern "C" void kernel_launch(void* const* d_in, const int* in_sizes, int n_in,
                              void* d_out, int out_size, void* d_ws, size_t ws_size,
                              hipStream_t stream)
{
  const float* x   = (const float*)d_in[0];
  const float* Wg  = (const float*)d_in[1];
  const float* bg  = (const float*)d_in[2];
  const float* Wp  = (const float*)d_in[3];
  const float* bp  = (const float*)d_in[4];
  const float* Wgg = (const float*)d_in[5];
  const float* bgg = (const float*)d_in[6];
  const float* W1  = (const float*)d_in[7];
  const float* b1  = (const float*)d_in[8];
  const float* W2  = (const float*)d_in[9];
  const float* b2  = (const float*)d_in[10];
  float* out = (float*)d_out;

  char* ws = (char*)d_ws;
  const size_t OFF_XH  = 0;
  const size_t OFF_W1T = OFF_XH  + (size_t)NB * ND * 2;           // 32 MB
  const size_t OFF_W2T = OFF_W1T + (size_t)NE * NP * ND * 2;      // +16 MB
  const size_t OFF_H   = OFF_W2T + (size_t)NE * ND * NP * 2;      // +16 MB
  const size_t OFF_ROWL= OFF_H   + (size_t)(2 * NB + 128) * NP * 2; // +~16 MB (padded)
  const size_t OFF_WL  = OFF_ROWL + (size_t)16 * NB * 4;
  const size_t OFF_CNT = OFF_WL  + (size_t)16 * NB * 4;
  const size_t OFF_PB  = OFF_CNT + 64;
  const size_t OFF_QM  = OFF_PB  + 64;

  half_t* xh   = (half_t*)(ws + OFF_XH);
  half_t* w1t  = (half_t*)(ws + OFF_W1T);
  half_t* w2t  = (half_t*)(ws + OFF_W2T);
  half_t* Hbuf = (half_t*)(ws + OFF_H);
  int*    rowl = (int*)(ws + OFF_ROWL);
  float*  wl   = (float*)(ws + OFF_WL);
  int*    cnt  = (int*)(ws + OFF_CNT);
  int*    pb   = (int*)(ws + OFF_PB);
  double* qm   = (double*)(ws + OFF_QM);

  hipMemsetAsync(cnt, 0, 64, stream);
  k_convert<<<NB, 256, 0, stream>>>(x, xh, qm);
  k_cvt_w<<<dim3(8192, 2, 1), 256, 0, stream>>>(W1, W2, w1t, w2t);
  k_gate<<<NB / 4, 256, 0, stream>>>(qm, Wg, bg, Wp, bp, Wgg, bgg, rowl, wl, cnt);
  k_prefix<<<1, 64, 0, stream>>>(cnt, pb);
  k_gemm1<<<dim3(4, 64, 16), 256, 0, stream>>>(xh, w1t, b1, rowl, cnt, pb, Hbuf);
  k_gemm2<<<dim3(16, 64, 8), 256, 0, stream>>>(Hbuf, w2t, b2, rowl, wl, cnt, pb, out, 0, 0);
  k_gemm2<<<dim3(16, 64, 8), 256, 0, stream>>>(Hbuf, w2t, b2, rowl, wl, cnt, pb, out, 8, 1);
}

// Round 3
// 398.735 us; speedup vs baseline: 1.4337x; 1.4337x over previous
//
#include <hip/hip_runtime.h>
#include <stdint.h>

#define NB 8192
#define ND 2048
#define NE 8
#define NG 4
#define NP 512
#define NH 192

typedef unsigned short u16;
typedef _Float16 half_t;
typedef half_t f16x8 __attribute__((ext_vector_type(8)));
typedef float f32x4 __attribute__((ext_vector_type(4)));

__device__ __forceinline__ void gload16(const void* g, void* l) {
  __builtin_amdgcn_global_load_lds(
      (const __attribute__((address_space(1))) void*)g,
      (__attribute__((address_space(3))) void*)l, 16, 0, 0);
}

// ---------------- x -> fp16 conversion + fp64 row mean ----------------
__global__ __launch_bounds__(256) void k_convert(
    const float* __restrict__ x, half_t* __restrict__ xh, double* __restrict__ qm)
{
  const int b = blockIdx.x;
  const int t = threadIdx.x;
  const float* xr = x + (size_t)b * ND;
  const float4 v0 = ((const float4*)xr)[t * 2];
  const float4 v1 = ((const float4*)xr)[t * 2 + 1];
  float f[8] = {v0.x, v0.y, v0.z, v0.w, v1.x, v1.y, v1.z, v1.w};
  double s = 0.0;
  __align__(16) half_t hb[8];
#pragma unroll
  for (int i = 0; i < 8; i++) { s += (double)f[i]; hb[i] = (half_t)f[i]; }
  *reinterpret_cast<int4*>(xh + (size_t)b * ND + t * 8) = *reinterpret_cast<const int4*>(hb);

#pragma unroll
  for (int m = 32; m >= 1; m >>= 1) s += __shfl_xor(s, m);
  __shared__ double part[4];
  if ((t & 63) == 0) part[t >> 6] = s;
  __syncthreads();
  if (t == 0) qm[b] = (part[0] + part[1] + part[2] + part[3]) / (double)ND;
}

// ---------------- gating: one wave per row, NO atomics ----------------
__global__ __launch_bounds__(256) void k_gate(
    const double* __restrict__ qm,
    const float* __restrict__ Wg, const float* __restrict__ bg,
    const float* __restrict__ Wp, const float* __restrict__ bp,
    const float* __restrict__ Wgg, const float* __restrict__ bgg,
    int* __restrict__ e0a, int* __restrict__ e1a,
    float* __restrict__ w0a, float* __restrict__ w1a)
{
  const int wave = threadIdx.x >> 6;
  const int lane = threadIdx.x & 63;
  const int b = blockIdx.x * 4 + wave;
  const double q = qm[b];

  double part = 0.0;
#pragma unroll
  for (int i = 0; i < 3; i++) {
    int h = lane + i * 64;  // 0..191
    double ang = q * (7.0 * (double)(h + 1));
    part += cos(ang) + sin(ang);
  }
#pragma unroll
  for (int m = 32; m >= 1; m >>= 1) part += __shfl_xor(part, m);
  const double tm = part / (2.0 * (double)NH);
  const double gi1 = 32.0 / 2048.0;  // mean spike rate is a constant (R0 analysis)

  double lg = -1.0e300;
  if (lane < 8) {
    const int e = lane, g = e & 3;
    lg = tm * (double)Wg[e] + gi1 * (double)Wg[NE + e] + (double)bg[e];
    lg -= 0.1 * (tm * (double)Wp[e] + gi1 * (double)Wp[NE + e] + (double)bp[e]);
    lg += tm * (double)Wgg[g] + gi1 * (double)Wgg[NG + g] + (double)bgg[g];
  }
  double mx = lg;
#pragma unroll
  for (int m = 4; m >= 1; m >>= 1) mx = fmax(mx, __shfl_xor(mx, m));
  double pe = 0.0;
  if (lane < 8) pe = exp(lg - mx);
  double ps = pe;
#pragma unroll
  for (int m = 4; m >= 1; m >>= 1) ps += __shfl_xor(ps, m);

  double lgs[8], pes[8];
#pragma unroll
  for (int e = 0; e < 8; e++) { lgs[e] = __shfl(lg, e); pes[e] = __shfl(pe, e); }

  if (lane == 0) {
    int e0 = 0;
    for (int e = 1; e < NE; e++) if (lgs[e] > lgs[e0]) e0 = e;
    int e1 = (e0 == 0) ? 1 : 0;
    for (int e = 0; e < NE; e++) if (e != e0 && lgs[e] > lgs[e1]) e1 = e;
    const double p0 = pes[e0] / ps;
    const double p1 = pes[e1] / ps;
    const double den = p0 + p1 + 1e-9;
    e0a[b] = e0; e1a[b] = e1;
    w0a[b] = (float)(p0 / den);
    w1a[b] = (float)(p1 / den);
  }
}

// ---------------- bucket build: LDS histogram, 16 global atomics/block ----------------
#define BUCKET_ROWS 256
__global__ __launch_bounds__(256) void k_bucket(
    const int* __restrict__ e0a, const int* __restrict__ e1a,
    const float* __restrict__ w0a, const float* __restrict__ w1a,
    int* __restrict__ rowl, float* __restrict__ wl, int* __restrict__ cnt)
{
  const int t = threadIdx.x;
  const int r = blockIdx.x * BUCKET_ROWS + t;
  __shared__ int hist[16];
  __shared__ int base[16];
  __shared__ int cursor[16];
  if (t < 16) { hist[t] = 0; cursor[t] = 0; }
  __syncthreads();

  const int e0 = e0a[r], e1 = e1a[r];
  atomicAdd(&hist[e0], 1);
  atomicAdd(&hist[8 + e1], 1);
  __syncthreads();
  if (t < 16) base[t] = atomicAdd(&cnt[t], hist[t]);
  __syncthreads();

  int p0 = atomicAdd(&cursor[e0], 1);
  rowl[e0 * NB + base[e0] + p0] = r;
  wl[e0 * NB + base[e0] + p0] = w0a[r];
  int p1 = atomicAdd(&cursor[8 + e1], 1);
  rowl[(8 + e1) * NB + base[8 + e1] + p1] = r;
  wl[(8 + e1) * NB + base[8 + e1] + p1] = w1a[r];
}

// ---------------- weight transpose + fp16 convert ----------------
__global__ __launch_bounds__(256) void k_cvt_w(
    const float* __restrict__ W1, const float* __restrict__ W2,
    half_t* __restrict__ w1t, half_t* __restrict__ w2t)
{
  const int which = blockIdx.y;
  const int R = which ? NP : ND;
  const int C = which ? ND : NP;
  const float* src = which ? W2 : W1;
  half_t* dst = which ? w2t : w1t;
  const int tiles_c = C >> 5;
  const int tiles_per_e = (R >> 5) * tiles_c;
  int id = blockIdx.x;
  int e = id / tiles_per_e;
  int rem = id - e * tiles_per_e;
  int tr = rem / tiles_c, tc = rem - tr * tiles_c;
  __shared__ float tile[32][33];
  const int tx = threadIdx.x & 31, ty = threadIdx.x >> 5;
  const float* s = src + (size_t)e * R * C + (size_t)(tr * 32) * C + tc * 32;
#pragma unroll
  for (int i = 0; i < 4; i++)
    tile[ty + i * 8][tx] = s[(size_t)(ty + i * 8) * C + tx];
  __syncthreads();
  half_t* d = dst + (size_t)e * R * C + (size_t)(tc * 32) * R + tr * 32;
#pragma unroll
  for (int i = 0; i < 4; i++)
    d[(size_t)(ty + i * 8) * R + tx] = (half_t)tile[tx][ty + i * 8];
}

__global__ void k_prefix(const int* __restrict__ cnt, int* __restrict__ pbase) {
  if (threadIdx.x == 0 && blockIdx.x == 0) {
    int s = 0;
    for (int i = 0; i < 16; i++) { pbase[i] = s; s += cnt[i]; }
  }
}

// ---------------- GEMM1: H = relu(gather(x) @ W1[e] + b1[e]) ----------------
__global__ __launch_bounds__(256) void k_gemm1(
    const half_t* __restrict__ xh, const half_t* __restrict__ w1t,
    const float* __restrict__ b1,
    const int* __restrict__ rowl, const int* __restrict__ cnt,
    const int* __restrict__ pbase, half_t* __restrict__ Hbuf)
{
  const int bucket = blockIdx.z;
  const int count = cnt[bucket];
  const int m0 = blockIdx.y * 128;
  if (m0 >= count) return;
  const int e = bucket & 7;
  const int n0 = blockIdx.x * 128;
  const int t = threadIdx.x;

  __shared__ __align__(16) half_t As[128 * 32];
  __shared__ __align__(16) half_t Bs[128 * 32];
  __shared__ int rows_s[128];

  if (t < 128) {
    int mi = m0 + t;
    rows_s[t] = rowl[bucket * NB + (mi < count ? mi : m0)];
  }
  __syncthreads();

  const int w = t >> 6, lane = t & 63;
  const int c0 = w * 128 + lane, c1 = c0 + 64;
  const half_t* gA0 = xh + (size_t)rows_s[c0 >> 2] * ND + (c0 & 3) * 8;
  const half_t* gA1 = xh + (size_t)rows_s[c1 >> 2] * ND + (c1 & 3) * 8;
  const half_t* w1te = w1t + (size_t)e * NP * ND;
  const half_t* gB0 = w1te + (size_t)(n0 + (c0 >> 2)) * ND + (c0 & 3) * 8;
  const half_t* gB1 = w1te + (size_t)(n0 + (c1 >> 2)) * ND + (c1 & 3) * 8;
  half_t* lA0 = As + (w * 128) * 8;
  half_t* lA1 = As + (w * 128 + 64) * 8;
  half_t* lB0 = Bs + (w * 128) * 8;
  half_t* lB1 = Bs + (w * 128 + 64) * 8;

  const int wr = w >> 1, wc = w & 1;
  const int lrow = lane & 15, lk = lane >> 4;

  f32x4 acc[4][4];
#pragma unroll
  for (int i = 0; i < 4; i++)
#pragma unroll
    for (int j = 0; j < 4; j++) {
      acc[i][j][0] = 0.f; acc[i][j][1] = 0.f; acc[i][j][2] = 0.f; acc[i][j][3] = 0.f;
    }

  for (int k0 = 0; k0 < ND; k0 += 32) {
    gload16(gA0 + k0, lA0);
    gload16(gA1 + k0, lA1);
    gload16(gB0 + k0, lB0);
    gload16(gB1 + k0, lB1);
    __syncthreads();
    f16x8 af[4], bf[4];
#pragma unroll
    for (int i = 0; i < 4; i++) {
      af[i] = *reinterpret_cast<const f16x8*>(&As[(wr * 64 + i * 16 + lrow) * 32 + lk * 8]);
      bf[i] = *reinterpret_cast<const f16x8*>(&Bs[(wc * 64 + i * 16 + lrow) * 32 + lk * 8]);
    }
#pragma unroll
    for (int mi = 0; mi < 4; mi++)
#pragma unroll
      for (int ni = 0; ni < 4; ni++)
        acc[mi][ni] = __builtin_amdgcn_mfma_f32_16x16x32_f16(af[mi], bf[ni], acc[mi][ni], 0, 0, 0);
    __syncthreads();
  }

  const int pb = pbase[bucket];
#pragma unroll
  for (int mi = 0; mi < 4; mi++) {
#pragma unroll
    for (int i = 0; i < 4; i++) {
      int lm = wr * 64 + mi * 16 + lk * 4 + i;
      if (m0 + lm < count) {
        size_t prow = (size_t)(pb + m0 + lm) * NP;
#pragma unroll
        for (int ni = 0; ni < 4; ni++) {
          int col = n0 + wc * 64 + ni * 16 + lrow;
          float v = acc[mi][ni][i] + b1[e * NP + col];
          Hbuf[prow + col] = (half_t)(v > 0.f ? v : 0.f);
        }
      }
    }
  }
}

// ---------------- GEMM2: out[r] (=|+=) w * (H @ W2[e] + b2[e]) ----------------
__global__ __launch_bounds__(256) void k_gemm2(
    const half_t* __restrict__ Hbuf, const half_t* __restrict__ w2t,
    const float* __restrict__ b2,
    const int* __restrict__ rowl, const float* __restrict__ wl,
    const int* __restrict__ cnt, const int* __restrict__ pbase,
    float* __restrict__ out, int bucket0, int addmode)
{
  const int bucket = bucket0 + blockIdx.z;
  const int count = cnt[bucket];
  const int m0 = blockIdx.y * 128;
  if (m0 >= count) return;
  const int e = bucket & 7;
  const int n0 = blockIdx.x * 128;
  const int t = threadIdx.x;

  __shared__ __align__(16) half_t As[128 * 32];
  __shared__ __align__(16) half_t Bs[128 * 32];
  __shared__ int rows_s[128];
  __shared__ float ws_s[128];

  if (t < 128) {
    int mi = m0 + t;
    int idx = bucket * NB + (mi < count ? mi : m0);
    rows_s[t] = rowl[idx];
    ws_s[t] = wl[idx];
  }
  __syncthreads();

  const int w = t >> 6, lane = t & 63;
  const int c0 = w * 128 + lane, c1 = c0 + 64;
  const int pb = pbase[bucket];
  const half_t* gA0 = Hbuf + (size_t)(pb + m0 + (c0 >> 2)) * NP + (c0 & 3) * 8;
  const half_t* gA1 = Hbuf + (size_t)(pb + m0 + (c1 >> 2)) * NP + (c1 & 3) * 8;
  const half_t* w2te = w2t + (size_t)e * ND * NP;
  const half_t* gB0 = w2te + (size_t)(n0 + (c0 >> 2)) * NP + (c0 & 3) * 8;
  const half_t* gB1 = w2te + (size_t)(n0 + (c1 >> 2)) * NP + (c1 & 3) * 8;
  half_t* lA0 = As + (w * 128) * 8;
  half_t* lA1 = As + (w * 128 + 64) * 8;
  half_t* lB0 = Bs + (w * 128) * 8;
  half_t* lB1 = Bs + (w * 128 + 64) * 8;

  const int wr = w >> 1, wc = w & 1;
  const int lrow = lane & 15, lk = lane >> 4;

  f32x4 acc[4][4];
#pragma unroll
  for (int i = 0; i < 4; i++)
#pragma unroll
    for (int j = 0; j < 4; j++) {
      acc[i][j][0] = 0.f; acc[i][j][1] = 0.f; acc[i][j][2] = 0.f; acc[i][j][3] = 0.f;
    }

  for (int k0 = 0; k0 < NP; k0 += 32) {
    gload16(gA0 + k0, lA0);
    gload16(gA1 + k0, lA1);
    gload16(gB0 + k0, lB0);
    gload16(gB1 + k0, lB1);
    __syncthreads();
    f16x8 af[4], bf[4];
#pragma unroll
    for (int i = 0; i < 4; i++) {
      af[i] = *reinterpret_cast<const f16x8*>(&As[(wr * 64 + i * 16 + lrow) * 32 + lk * 8]);
      bf[i] = *reinterpret_cast<const f16x8*>(&Bs[(wc * 64 + i * 16 + lrow) * 32 + lk * 8]);
    }
#pragma unroll
    for (int mi = 0; mi < 4; mi++)
#pragma unroll
      for (int ni = 0; ni < 4; ni++)
        acc[mi][ni] = __builtin_amdgcn_mfma_f32_16x16x32_f16(af[mi], bf[ni], acc[mi][ni], 0, 0, 0);
    __syncthreads();
  }

#pragma unroll
  for (int mi = 0; mi < 4; mi++) {
#pragma unroll
    for (int i = 0; i < 4; i++) {
      int lm = wr * 64 + mi * 16 + lk * 4 + i;
      if (m0 + lm < count) {
        int r = rows_s[lm];
        float wgt = ws_s[lm];
        float* orow = out + (size_t)r * ND;
#pragma unroll
        for (int ni = 0; ni < 4; ni++) {
          int col = n0 + wc * 64 + ni * 16 + lrow;
          float v = (acc[mi][ni][i] + b2[e * ND + col]) * wgt;
          if (addmode) orow[col] += v;
          else orow[col] = v;
        }
      }
    }
  }
}

extern "C" void kernel_launch(void* const* d_in, const int* in_sizes, int n_in,
                              void* d_out, int out_size, void* d_ws, size_t ws_size,
                              hipStream_t stream)
{
  const float* x   = (const float*)d_in[0];
  const float* Wg  = (const float*)d_in[1];
  const float* bg  = (const float*)d_in[2];
  const float* Wp  = (const float*)d_in[3];
  const float* bp  = (const float*)d_in[4];
  const float* Wgg = (const float*)d_in[5];
  const float* bgg = (const float*)d_in[6];
  const float* W1  = (const float*)d_in[7];
  const float* b1  = (const float*)d_in[8];
  const float* W2  = (const float*)d_in[9];
  const float* b2  = (const float*)d_in[10];
  float* out = (float*)d_out;

  char* ws = (char*)d_ws;
  const size_t OFF_XH  = 0;
  const size_t OFF_W1T = OFF_XH  + (size_t)NB * ND * 2;             // 32 MB
  const size_t OFF_W2T = OFF_W1T + (size_t)NE * NP * ND * 2;        // +16 MB
  const size_t OFF_H   = OFF_W2T + (size_t)NE * ND * NP * 2;        // +16 MB
  const size_t OFF_ROWL= OFF_H   + (size_t)(2 * NB + 128) * NP * 2; // +~17 MB
  const size_t OFF_WL  = OFF_ROWL + (size_t)16 * NB * 4;
  const size_t OFF_CNT = OFF_WL  + (size_t)16 * NB * 4;
  const size_t OFF_PB  = OFF_CNT + 64;
  const size_t OFF_QM  = OFF_PB  + 64;
  const size_t OFF_E0  = OFF_QM  + (size_t)NB * 8;
  const size_t OFF_E1  = OFF_E0  + (size_t)NB * 4;
  const size_t OFF_W0  = OFF_E1  + (size_t)NB * 4;
  const size_t OFF_W1A = OFF_W0  + (size_t)NB * 4;

  half_t* xh   = (half_t*)(ws + OFF_XH);
  half_t* w1t  = (half_t*)(ws + OFF_W1T);
  half_t* w2t  = (half_t*)(ws + OFF_W2T);
  half_t* Hbuf = (half_t*)(ws + OFF_H);
  int*    rowl = (int*)(ws + OFF_ROWL);
  float*  wl   = (float*)(ws + OFF_WL);
  int*    cnt  = (int*)(ws + OFF_CNT);
  int*    pb   = (int*)(ws + OFF_PB);
  double* qm   = (double*)(ws + OFF_QM);
  int*    e0a  = (int*)(ws + OFF_E0);
  int*    e1a  = (int*)(ws + OFF_E1);
  float*  w0a  = (float*)(ws + OFF_W0);
  float*  w1a  = (float*)(ws + OFF_W1A);

  hipMemsetAsync(cnt, 0, 64, stream);
  k_convert<<<NB, 256, 0, stream>>>(x, xh, qm);
  k_cvt_w<<<dim3(8192, 2, 1), 256, 0, stream>>>(W1, W2, w1t, w2t);
  k_gate<<<NB / 4, 256, 0, stream>>>(qm, Wg, bg, Wp, bp, Wgg, bgg, e0a, e1a, w0a, w1a);
  k_bucket<<<NB / BUCKET_ROWS, BUCKET_ROWS, 0, stream>>>(e0a, e1a, w0a, w1a, rowl, wl, cnt);
  k_prefix<<<1, 64, 0, stream>>>(cnt, pb);
  k_gemm1<<<dim3(4, 64, 16), 256, 0, stream>>>(xh, w1t, b1, rowl, cnt, pb, Hbuf);
  k_gemm2<<<dim3(16, 64, 8), 256, 0, stream>>>(Hbuf, w2t, b2, rowl, wl, cnt, pb, out, 0, 0);
  k_gemm2<<<dim3(16, 64, 8), 256, 0, stream>>>(Hbuf, w2t, b2, rowl, wl, cnt, pb, out, 8, 1);
}

// Round 5
// 355.438 us; speedup vs baseline: 1.6083x; 1.1218x over previous
//
#include <hip/hip_runtime.h>
#include <stdint.h>

#define NB 8192
#define ND 2048
#define NE 8
#define NG 4
#define NP 512
#define NH 192

typedef _Float16 half_t;
typedef half_t f16x8 __attribute__((ext_vector_type(8)));
typedef float f32x4 __attribute__((ext_vector_type(4)));

__device__ __forceinline__ void gload16(const void* g, void* l) {
  __builtin_amdgcn_global_load_lds(
      (const __attribute__((address_space(1))) void*)g,
      (__attribute__((address_space(3))) void*)l, 16, 0, 0);
}

// ---------------- x -> fp16 conversion + fp64 row mean ----------------
__global__ __launch_bounds__(256) void k_convert(
    const float* __restrict__ x, half_t* __restrict__ xh, double* __restrict__ qm)
{
  const int b = blockIdx.x;
  const int t = threadIdx.x;
  const float* xr = x + (size_t)b * ND;
  const float4 v0 = ((const float4*)xr)[t * 2];
  const float4 v1 = ((const float4*)xr)[t * 2 + 1];
  float f[8] = {v0.x, v0.y, v0.z, v0.w, v1.x, v1.y, v1.z, v1.w};
  double s = 0.0;
  __align__(16) half_t hb[8];
#pragma unroll
  for (int i = 0; i < 8; i++) { s += (double)f[i]; hb[i] = (half_t)f[i]; }
  *reinterpret_cast<int4*>(xh + (size_t)b * ND + t * 8) = *reinterpret_cast<const int4*>(hb);

#pragma unroll
  for (int m = 32; m >= 1; m >>= 1) s += __shfl_xor(s, m);
  __shared__ double part[4];
  if ((t & 63) == 0) part[t >> 6] = s;
  __syncthreads();
  if (t == 0) qm[b] = (part[0] + part[1] + part[2] + part[3]) / (double)ND;
}

// ---------------- gating: one wave per row, NO atomics ----------------
__global__ __launch_bounds__(256) void k_gate(
    const double* __restrict__ qm,
    const float* __restrict__ Wg, const float* __restrict__ bg,
    const float* __restrict__ Wp, const float* __restrict__ bp,
    const float* __restrict__ Wgg, const float* __restrict__ bgg,
    int* __restrict__ e0a, int* __restrict__ e1a,
    float* __restrict__ w0a, float* __restrict__ w1a)
{
  const int wave = threadIdx.x >> 6;
  const int lane = threadIdx.x & 63;
  const int b = blockIdx.x * 4 + wave;
  const double q = qm[b];

  double part = 0.0;
#pragma unroll
  for (int i = 0; i < 3; i++) {
    int h = lane + i * 64;  // 0..191
    double ang = q * (7.0 * (double)(h + 1));
    part += cos(ang) + sin(ang);
  }
#pragma unroll
  for (int m = 32; m >= 1; m >>= 1) part += __shfl_xor(part, m);
  const double tm = part / (2.0 * (double)NH);
  const double gi1 = 32.0 / 2048.0;  // mean spike rate is a constant (R0 analysis)

  double lg = -1.0e300;
  if (lane < 8) {
    const int e = lane, g = e & 3;
    lg = tm * (double)Wg[e] + gi1 * (double)Wg[NE + e] + (double)bg[e];
    lg -= 0.1 * (tm * (double)Wp[e] + gi1 * (double)Wp[NE + e] + (double)bp[e]);
    lg += tm * (double)Wgg[g] + gi1 * (double)Wgg[NG + g] + (double)bgg[g];
  }
  double mx = lg;
#pragma unroll
  for (int m = 4; m >= 1; m >>= 1) mx = fmax(mx, __shfl_xor(mx, m));
  double pe = 0.0;
  if (lane < 8) pe = exp(lg - mx);
  double ps = pe;
#pragma unroll
  for (int m = 4; m >= 1; m >>= 1) ps += __shfl_xor(ps, m);

  double lgs[8], pes[8];
#pragma unroll
  for (int e = 0; e < 8; e++) { lgs[e] = __shfl(lg, e); pes[e] = __shfl(pe, e); }

  if (lane == 0) {
    int e0 = 0;
    for (int e = 1; e < NE; e++) if (lgs[e] > lgs[e0]) e0 = e;
    int e1 = (e0 == 0) ? 1 : 0;
    for (int e = 0; e < NE; e++) if (e != e0 && lgs[e] > lgs[e1]) e1 = e;
    const double p0 = pes[e0] / ps;
    const double p1 = pes[e1] / ps;
    const double den = p0 + p1 + 1e-9;
    e0a[b] = e0; e1a[b] = e1;
    w0a[b] = (float)(p0 / den);
    w1a[b] = (float)(p1 / den);
  }
}

// ---------------- bucket build: slot-expert buckets + pair buckets ----------------
__global__ __launch_bounds__(256) void k_bucket(
    const int* __restrict__ e0a, const int* __restrict__ e1a,
    const float* __restrict__ w0a, const float* __restrict__ w1a,
    int* __restrict__ rowl, float* __restrict__ wl, int* __restrict__ cnt,
    int* __restrict__ pos0a, int* __restrict__ pos1a,
    int* __restrict__ rowlp, int* __restrict__ cntp)
{
  const int t = threadIdx.x;
  const int r = blockIdx.x * 256 + t;
  __shared__ int hist[16], base[16], cursor[16];
  __shared__ int histp[64], basep[64], cursorp[64];
  if (t < 16) { hist[t] = 0; cursor[t] = 0; }
  if (t < 64) { histp[t] = 0; cursorp[t] = 0; }
  __syncthreads();

  const int e0 = e0a[r], e1 = e1a[r];
  const int p = e0 * 8 + e1;
  atomicAdd(&hist[e0], 1);
  atomicAdd(&hist[8 + e1], 1);
  atomicAdd(&histp[p], 1);
  __syncthreads();
  if (t < 16) base[t] = atomicAdd(&cnt[t], hist[t]);
  if (t < 64) basep[t] = atomicAdd(&cntp[t], histp[t]);
  __syncthreads();

  int p0 = atomicAdd(&cursor[e0], 1);
  int idx0 = base[e0] + p0;
  rowl[e0 * NB + idx0] = r;
  wl[e0 * NB + idx0] = w0a[r];
  pos0a[r] = idx0;

  int p1 = atomicAdd(&cursor[8 + e1], 1);
  int idx1 = base[8 + e1] + p1;
  rowl[(8 + e1) * NB + idx1] = r;
  wl[(8 + e1) * NB + idx1] = w1a[r];
  pos1a[r] = idx1;

  int pp = atomicAdd(&cursorp[p], 1);
  rowlp[p * NB + basep[p] + pp] = r;
}

// ---------------- weight transpose + fp16 convert ----------------
__global__ __launch_bounds__(256) void k_cvt_w(
    const float* __restrict__ W1, const float* __restrict__ W2,
    half_t* __restrict__ w1t, half_t* __restrict__ w2t)
{
  const int which = blockIdx.y;
  const int R = which ? NP : ND;
  const int C = which ? ND : NP;
  const float* src = which ? W2 : W1;
  half_t* dst = which ? w2t : w1t;
  const int tiles_c = C >> 5;
  const int tiles_per_e = (R >> 5) * tiles_c;
  int id = blockIdx.x;
  int e = id / tiles_per_e;
  int rem = id - e * tiles_per_e;
  int tr = rem / tiles_c, tc = rem - tr * tiles_c;
  __shared__ float tile[32][33];
  const int tx = threadIdx.x & 31, ty = threadIdx.x >> 5;
  const float* s = src + (size_t)e * R * C + (size_t)(tr * 32) * C + tc * 32;
#pragma unroll
  for (int i = 0; i < 4; i++)
    tile[ty + i * 8][tx] = s[(size_t)(ty + i * 8) * C + tx];
  __syncthreads();
  half_t* d = dst + (size_t)e * R * C + (size_t)(tc * 32) * R + tr * 32;
#pragma unroll
  for (int i = 0; i < 4; i++)
    d[(size_t)(ty + i * 8) * R + tx] = (half_t)tile[tx][ty + i * 8];
}

// ---------------- prefix + compact work-item lists ----------------
__global__ void k_prefix(const int* __restrict__ cnt, const int* __restrict__ cntp,
                         int* __restrict__ pbase,
                         int* __restrict__ i16b, int* __restrict__ i16m, int* __restrict__ n16,
                         int* __restrict__ ipp, int* __restrict__ ipm, int* __restrict__ np)
{
  if (threadIdx.x == 0 && blockIdx.x == 0) {
    int s = 0;
    for (int i = 0; i < 16; i++) { pbase[i] = s; s += cnt[i]; }
    int t = 0;
    for (int b = 0; b < 16; b++)
      for (int m0 = 0; m0 < cnt[b]; m0 += 128) { i16b[t] = b; i16m[t] = m0; t++; }
    *n16 = t;
    t = 0;
    for (int p = 0; p < 64; p++)
      for (int m0 = 0; m0 < cntp[p]; m0 += 128) { ipp[t] = p; ipm[t] = m0; t++; }
    *np = t;
  }
}

// ---------------- GEMM1: H = w * relu(gather(x) @ W1[e] + b1[e]) ----------------
__global__ __launch_bounds__(256) void k_gemm1(
    const half_t* __restrict__ xh, const half_t* __restrict__ w1t,
    const float* __restrict__ b1,
    const int* __restrict__ rowl, const float* __restrict__ wl,
    const int* __restrict__ cnt, const int* __restrict__ pbase,
    const int* __restrict__ i16b, const int* __restrict__ i16m,
    const int* __restrict__ n16, half_t* __restrict__ Hbuf)
{
  const int wi = blockIdx.y;
  if (wi >= *n16) return;
  const int bucket = i16b[wi];
  const int m0 = i16m[wi];
  const int count = cnt[bucket];
  const int e = bucket & 7;
  const int n0 = blockIdx.x * 128;
  const int t = threadIdx.x;

  __shared__ __align__(16) half_t As[128 * 32];
  __shared__ __align__(16) half_t Bs[128 * 32];
  __shared__ int rows_s[128];
  __shared__ float ws_s[128];

  if (t < 128) {
    int mi = m0 + t;
    int idx = bucket * NB + (mi < count ? mi : m0);
    rows_s[t] = rowl[idx];
    ws_s[t] = wl[idx];
  }
  __syncthreads();

  const int w = t >> 6, lane = t & 63;
  const int c0 = w * 128 + lane, c1 = c0 + 64;
  const half_t* gA0 = xh + (size_t)rows_s[c0 >> 2] * ND + (c0 & 3) * 8;
  const half_t* gA1 = xh + (size_t)rows_s[c1 >> 2] * ND + (c1 & 3) * 8;
  const half_t* w1te = w1t + (size_t)e * NP * ND;
  const half_t* gB0 = w1te + (size_t)(n0 + (c0 >> 2)) * ND + (c0 & 3) * 8;
  const half_t* gB1 = w1te + (size_t)(n0 + (c1 >> 2)) * ND + (c1 & 3) * 8;
  half_t* lA0 = As + (w * 128) * 8;
  half_t* lA1 = As + (w * 128 + 64) * 8;
  half_t* lB0 = Bs + (w * 128) * 8;
  half_t* lB1 = Bs + (w * 128 + 64) * 8;

  const int wr = w >> 1, wc = w & 1;
  const int lrow = lane & 15, lk = lane >> 4;

  f32x4 acc[4][4];
#pragma unroll
  for (int i = 0; i < 4; i++)
#pragma unroll
    for (int j = 0; j < 4; j++) {
      acc[i][j][0] = 0.f; acc[i][j][1] = 0.f; acc[i][j][2] = 0.f; acc[i][j][3] = 0.f;
    }

  for (int k0 = 0; k0 < ND; k0 += 32) {
    gload16(gA0 + k0, lA0);
    gload16(gA1 + k0, lA1);
    gload16(gB0 + k0, lB0);
    gload16(gB1 + k0, lB1);
    __syncthreads();
    f16x8 af[4], bf[4];
#pragma unroll
    for (int i = 0; i < 4; i++) {
      af[i] = *reinterpret_cast<const f16x8*>(&As[(wr * 64 + i * 16 + lrow) * 32 + lk * 8]);
      bf[i] = *reinterpret_cast<const f16x8*>(&Bs[(wc * 64 + i * 16 + lrow) * 32 + lk * 8]);
    }
#pragma unroll
    for (int mi = 0; mi < 4; mi++)
#pragma unroll
      for (int ni = 0; ni < 4; ni++)
        acc[mi][ni] = __builtin_amdgcn_mfma_f32_16x16x32_f16(af[mi], bf[ni], acc[mi][ni], 0, 0, 0);
    __syncthreads();
  }

  const int pb = pbase[bucket];
#pragma unroll
  for (int mi = 0; mi < 4; mi++) {
#pragma unroll
    for (int i = 0; i < 4; i++) {
      int lm = wr * 64 + mi * 16 + lk * 4 + i;
      if (m0 + lm < count) {
        size_t prow = (size_t)(pb + m0 + lm) * NP;
        float wcoef = ws_s[lm];
#pragma unroll
        for (int ni = 0; ni < 4; ni++) {
          int col = n0 + wc * 64 + ni * 16 + lrow;
          float v = acc[mi][ni][i] + b1[e * NP + col];
          v = v > 0.f ? v : 0.f;
          Hbuf[prow + col] = (half_t)(v * wcoef);  // pre-scale by gate weight
        }
      }
    }
  }
}

// ---- GEMM2 (pair-fused): out[r] = H0w@W2[e0] + H1w@W2[e1] + w0*b2[e0] + w1*b2[e1] ----
__global__ __launch_bounds__(256) void k_gemm2p(
    const half_t* __restrict__ Hbuf, const half_t* __restrict__ w2t,
    const float* __restrict__ b2,
    const int* __restrict__ rowlp, const int* __restrict__ cntp,
    const int* __restrict__ pbase,
    const int* __restrict__ pos0a, const int* __restrict__ pos1a,
    const float* __restrict__ w0a, const float* __restrict__ w1a,
    const int* __restrict__ ipp, const int* __restrict__ ipm,
    const int* __restrict__ np, float* __restrict__ out)
{
  const int wi = blockIdx.y;
  if (wi >= *np) return;
  const int p = ipp[wi];
  const int m0 = ipm[wi];
  const int count = cntp[p];
  const int e0 = p >> 3, e1 = p & 7;
  const int n0 = blockIdx.x * 128;
  const int t = threadIdx.x;

  __shared__ __align__(16) half_t As[128 * 32];
  __shared__ __align__(16) half_t Bs[128 * 32];
  __shared__ int h0_s[128], h1_s[128], rs_s[128];
  __shared__ float w0_s[128], w1_s[128];

  if (t < 128) {
    int mi = m0 + t;
    int r = rowlp[p * NB + (mi < count ? mi : m0)];
    rs_s[t] = r;
    h0_s[t] = pbase[e0] + pos0a[r];
    h1_s[t] = pbase[8 + e1] + pos1a[r];
    w0_s[t] = w0a[r];
    w1_s[t] = w1a[r];
  }
  __syncthreads();

  const int w = t >> 6, lane = t & 63;
  const int c0 = w * 128 + lane, c1 = c0 + 64;
  const half_t* w2e0 = w2t + (size_t)e0 * ND * NP;
  const half_t* w2e1 = w2t + (size_t)e1 * ND * NP;
  const half_t* gB0e0 = w2e0 + (size_t)(n0 + (c0 >> 2)) * NP + (c0 & 3) * 8;
  const half_t* gB1e0 = w2e0 + (size_t)(n0 + (c1 >> 2)) * NP + (c1 & 3) * 8;
  const half_t* gB0e1 = w2e1 + (size_t)(n0 + (c0 >> 2)) * NP + (c0 & 3) * 8;
  const half_t* gB1e1 = w2e1 + (size_t)(n0 + (c1 >> 2)) * NP + (c1 & 3) * 8;
  const half_t* gA0s0 = Hbuf + (size_t)h0_s[c0 >> 2] * NP + (c0 & 3) * 8;
  const half_t* gA1s0 = Hbuf + (size_t)h0_s[c1 >> 2] * NP + (c1 & 3) * 8;
  const half_t* gA0s1 = Hbuf + (size_t)h1_s[c0 >> 2] * NP + (c0 & 3) * 8;
  const half_t* gA1s1 = Hbuf + (size_t)h1_s[c1 >> 2] * NP + (c1 & 3) * 8;
  half_t* lA0 = As + (w * 128) * 8;
  half_t* lA1 = As + (w * 128 + 64) * 8;
  half_t* lB0 = Bs + (w * 128) * 8;
  half_t* lB1 = Bs + (w * 128 + 64) * 8;

  const int wr = w >> 1, wc = w & 1;
  const int lrow = lane & 15, lk = lane >> 4;

  f32x4 acc[4][4];
#pragma unroll
  for (int i = 0; i < 4; i++)
#pragma unroll
    for (int j = 0; j < 4; j++) {
      acc[i][j][0] = 0.f; acc[i][j][1] = 0.f; acc[i][j][2] = 0.f; acc[i][j][3] = 0.f;
    }

  // segment 0: slot-0 hidden rows vs W2[e0]
  for (int k0 = 0; k0 < NP; k0 += 32) {
    gload16(gA0s0 + k0, lA0);
    gload16(gA1s0 + k0, lA1);
    gload16(gB0e0 + k0, lB0);
    gload16(gB1e0 + k0, lB1);
    __syncthreads();
    f16x8 af[4], bf[4];
#pragma unroll
    for (int i = 0; i < 4; i++) {
      af[i] = *reinterpret_cast<const f16x8*>(&As[(wr * 64 + i * 16 + lrow) * 32 + lk * 8]);
      bf[i] = *reinterpret_cast<const f16x8*>(&Bs[(wc * 64 + i * 16 + lrow) * 32 + lk * 8]);
    }
#pragma unroll
    for (int mi = 0; mi < 4; mi++)
#pragma unroll
      for (int ni = 0; ni < 4; ni++)
        acc[mi][ni] = __builtin_amdgcn_mfma_f32_16x16x32_f16(af[mi], bf[ni], acc[mi][ni], 0, 0, 0);
    __syncthreads();
  }
  // segment 1: slot-1 hidden rows vs W2[e1]
  for (int k0 = 0; k0 < NP; k0 += 32) {
    gload16(gA0s1 + k0, lA0);
    gload16(gA1s1 + k0, lA1);
    gload16(gB0e1 + k0, lB0);
    gload16(gB1e1 + k0, lB1);
    __syncthreads();
    f16x8 af[4], bf[4];
#pragma unroll
    for (int i = 0; i < 4; i++) {
      af[i] = *reinterpret_cast<const f16x8*>(&As[(wr * 64 + i * 16 + lrow) * 32 + lk * 8]);
      bf[i] = *reinterpret_cast<const f16x8*>(&Bs[(wc * 64 + i * 16 + lrow) * 32 + lk * 8]);
    }
#pragma unroll
    for (int mi = 0; mi < 4; mi++)
#pragma unroll
      for (int ni = 0; ni < 4; ni++)
        acc[mi][ni] = __builtin_amdgcn_mfma_f32_16x16x32_f16(af[mi], bf[ni], acc[mi][ni], 0, 0, 0);
    __syncthreads();
  }

  // epilogue: single write of the combined row
  float b20[4], b21[4];
#pragma unroll
  for (int ni = 0; ni < 4; ni++) {
    int col = n0 + wc * 64 + ni * 16 + lrow;
    b20[ni] = b2[e0 * ND + col];
    b21[ni] = b2[e1 * ND + col];
  }
#pragma unroll
  for (int mi = 0; mi < 4; mi++) {
#pragma unroll
    for (int i = 0; i < 4; i++) {
      int lm = wr * 64 + mi * 16 + lk * 4 + i;
      if (m0 + lm < count) {
        int r = rs_s[lm];
        float wb0 = w0_s[lm], wb1 = w1_s[lm];
        float* orow = out + (size_t)r * ND;
#pragma unroll
        for (int ni = 0; ni < 4; ni++) {
          int col = n0 + wc * 64 + ni * 16 + lrow;
          orow[col] = acc[mi][ni][i] + wb0 * b20[ni] + wb1 * b21[ni];
        }
      }
    }
  }
}

extern "C" void kernel_launch(void* const* d_in, const int* in_sizes, int n_in,
                              void* d_out, int out_size, void* d_ws, size_t ws_size,
                              hipStream_t stream)
{
  const float* x   = (const float*)d_in[0];
  const float* Wg  = (const float*)d_in[1];
  const float* bg  = (const float*)d_in[2];
  const float* Wp  = (const float*)d_in[3];
  const float* bp  = (const float*)d_in[4];
  const float* Wgg = (const float*)d_in[5];
  const float* bgg = (const float*)d_in[6];
  const float* W1  = (const float*)d_in[7];
  const float* b1  = (const float*)d_in[8];
  const float* W2  = (const float*)d_in[9];
  const float* b2  = (const float*)d_in[10];
  float* out = (float*)d_out;

  char* ws = (char*)d_ws;
  size_t off = 0;
  const size_t OFF_XH   = off; off += (size_t)NB * ND * 2;              // 32 MB
  const size_t OFF_W1T  = off; off += (size_t)NE * NP * ND * 2;         // 16 MB
  const size_t OFF_W2T  = off; off += (size_t)NE * ND * NP * 2;         // 16 MB
  const size_t OFF_H    = off; off += (size_t)(2 * NB + 128) * NP * 2;  // ~17 MB
  const size_t OFF_ROWL = off; off += (size_t)16 * NB * 4;
  const size_t OFF_WL   = off; off += (size_t)16 * NB * 4;
  const size_t OFF_ROWLP= off; off += (size_t)64 * NB * 4;              // 2 MB
  const size_t OFF_CNT  = off; off += 64;
  const size_t OFF_CNTP = off; off += 256;
  const size_t OFF_PB   = off; off += 64;
  const size_t OFF_QM   = off; off += (size_t)NB * 8;
  const size_t OFF_E0   = off; off += (size_t)NB * 4;
  const size_t OFF_E1   = off; off += (size_t)NB * 4;
  const size_t OFF_W0   = off; off += (size_t)NB * 4;
  const size_t OFF_W1A  = off; off += (size_t)NB * 4;
  const size_t OFF_POS0 = off; off += (size_t)NB * 4;
  const size_t OFF_POS1 = off; off += (size_t)NB * 4;
  const size_t OFF_I16B = off; off += 1024;
  const size_t OFF_I16M = off; off += 1024;
  const size_t OFF_N16  = off; off += 64;
  const size_t OFF_IPP  = off; off += 1024;
  const size_t OFF_IPM  = off; off += 1024;
  const size_t OFF_NP   = off; off += 64;

  half_t* xh   = (half_t*)(ws + OFF_XH);
  half_t* w1t  = (half_t*)(ws + OFF_W1T);
  half_t* w2t  = (half_t*)(ws + OFF_W2T);
  half_t* Hbuf = (half_t*)(ws + OFF_H);
  int*    rowl = (int*)(ws + OFF_ROWL);
  float*  wl   = (float*)(ws + OFF_WL);
  int*    rowlp= (int*)(ws + OFF_ROWLP);
  int*    cnt  = (int*)(ws + OFF_CNT);
  int*    cntp = (int*)(ws + OFF_CNTP);
  int*    pb   = (int*)(ws + OFF_PB);
  double* qm   = (double*)(ws + OFF_QM);
  int*    e0a  = (int*)(ws + OFF_E0);
  int*    e1a  = (int*)(ws + OFF_E1);
  float*  w0a  = (float*)(ws + OFF_W0);
  float*  w1a  = (float*)(ws + OFF_W1A);
  int*    pos0a= (int*)(ws + OFF_POS0);
  int*    pos1a= (int*)(ws + OFF_POS1);
  int*    i16b = (int*)(ws + OFF_I16B);
  int*    i16m = (int*)(ws + OFF_I16M);
  int*    n16  = (int*)(ws + OFF_N16);
  int*    ipp  = (int*)(ws + OFF_IPP);
  int*    ipm  = (int*)(ws + OFF_IPM);
  int*    np   = (int*)(ws + OFF_NP);

  hipMemsetAsync(cnt, 0, 64 + 256, stream);  // cnt + cntp are contiguous
  k_convert<<<NB, 256, 0, stream>>>(x, xh, qm);
  k_cvt_w<<<dim3(8192, 2, 1), 256, 0, stream>>>(W1, W2, w1t, w2t);
  k_gate<<<NB / 4, 256, 0, stream>>>(qm, Wg, bg, Wp, bp, Wgg, bgg, e0a, e1a, w0a, w1a);
  k_bucket<<<NB / 256, 256, 0, stream>>>(e0a, e1a, w0a, w1a, rowl, wl, cnt,
                                         pos0a, pos1a, rowlp, cntp);
  k_prefix<<<1, 64, 0, stream>>>(cnt, cntp, pb, i16b, i16m, n16, ipp, ipm, np);
  // n16 worst case: 16384/128 + 16 partial tiles = 144  (R3 bug: was 80 -> half of H poisoned)
  k_gemm1<<<dim3(4, 144, 1), 256, 0, stream>>>(xh, w1t, b1, rowl, wl, cnt, pb,
                                               i16b, i16m, n16, Hbuf);
  // np worst case: 8192/128 + 64 partial tiles = 128
  k_gemm2p<<<dim3(16, 128, 1), 256, 0, stream>>>(Hbuf, w2t, b2, rowlp, cntp, pb,
                                                 pos0a, pos1a, w0a, w1a, ipp, ipm, np, out);
}